// Round 16
// baseline (115.384 us; speedup 1.0000x reference)
//
#include <hip/hip_runtime.h>
#include <string.h>

#define N_NODES   50000
#define N_EDGES   640000
#define DIM       128
#define NUM_GRAPHS 64
#define SLOTS     64   // max in-degree slot capacity; P(deg>=64 | lambda=12.8) ~ 3e-23/node
#define GEMM1_BLOCKS 196   // ceil(N_NODES/256)
#define FILL_BLOCKS  157   // ceil(N_EDGES / (512*8))

typedef __attribute__((ext_vector_type(8))) short          s16x8;
typedef __attribute__((ext_vector_type(8))) unsigned short u16x8;
typedef __attribute__((ext_vector_type(8))) unsigned char  u8x8;
typedef __attribute__((ext_vector_type(4))) float          f32x4;

__device__ inline float bf2f(unsigned short u) {
    unsigned v = ((unsigned)u) << 16;
    float f;
    __builtin_memcpy(&f, &v, 4);
    return f;
}
__device__ inline unsigned short f2bf(float f) {
    unsigned u;
    __builtin_memcpy(&u, &f, 4);
    u = (u + 0x7fffu + ((u >> 16) & 1u)) >> 16;   // RNE
    return (unsigned short)u;
}

// ---------------- fp8 e4m3 (OCP) helpers ----------------
__device__ inline float fp8_to_f32(unsigned char b) {
#if defined(__has_builtin)
#if __has_builtin(__builtin_amdgcn_cvt_f32_fp8)
    return __builtin_amdgcn_cvt_f32_fp8((int)b, 0);
#else
    unsigned s = (b >> 7) & 1u, em = b & 0x7fu;
    unsigned bits = (s << 31) | (em << 20);
    float x;
    __builtin_memcpy(&x, &bits, 4);
    return x * 0x1.0p+120f;
#endif
#else
    unsigned s = (b >> 7) & 1u, em = b & 0x7fu;
    unsigned bits = (s << 31) | (em << 20);
    float x;
    __builtin_memcpy(&x, &bits, 4);
    return x * 0x1.0p+120f;
#endif
}

__device__ inline unsigned char f32_to_fp8(float v) {
#if defined(__has_builtin)
#if __has_builtin(__builtin_amdgcn_cvt_pk_fp8_f32)
    int r = __builtin_amdgcn_cvt_pk_fp8_f32(v, v, 0, false);
    return (unsigned char)(r & 0xff);
#define FP8_HW_ENC 1
#endif
#endif
#ifndef FP8_HW_ENC
    unsigned bits;
    __builtin_memcpy(&bits, &v, 4);
    unsigned s = bits >> 31;
    float av = fabsf(v);
    if (av < 0x1.0p-10f) return (unsigned char)(s << 7);
    if (av >= 448.f)     return (unsigned char)((s << 7) | 0x7E);
    int e = (int)((bits >> 23) & 0xFF) - 127;
    unsigned m = bits & 0x7FFFFF;
    if (e >= -6) {
        unsigned r = m + 0x0FFFFF + ((m >> 20) & 1);
        unsigned mm = r >> 20;
        unsigned ee = (unsigned)(e + 7);
        if (mm >= 8) { mm = 0; ee += 1; }
        if (ee >= 16) return (unsigned char)((s << 7) | 0x7E);
        return (unsigned char)((s << 7) | (ee << 3) | mm);
    } else {
        float scaled = av * 0x1.0p+9f;
        int d = (int)(scaled + 0.5f);
        if (d >= 8) return (unsigned char)((s << 7) | (1u << 3));
        return (unsigned char)((s << 7) | (unsigned)d);
    }
#endif
}

// ================================================================ weight prep (W1 only) + zeroing
__global__ __launch_bounds__(128) void k_prep_w(const float* __restrict__ W1,
                                                unsigned short* __restrict__ Wt1,
                                                int* __restrict__ cnt,
                                                float* __restrict__ pooled) {
    int k = blockIdx.x;            // 0..127
    int n = threadIdx.x;
    Wt1[n * DIM + k] = f2bf(W1[k * DIM + n]);

    int gid = blockIdx.x * 128 + threadIdx.x;          // 16384 threads
    for (int i = gid; i < N_NODES; i += 16384) cnt[i] = 0;
    if (gid < NUM_GRAPHS * DIM) pooled[gid] = 0.f;
}

// ================================================================ GEMM1 || fill_slots (block-range fused)
// blocks [0, GEMM1_BLOCKS): H1 = fp8(x @ W1); rest: 8-edge/thread slotted fill
__global__ __launch_bounds__(512) void k_fill_gemm1(const int* __restrict__ src,
                                                    const int* __restrict__ dst,
                                                    int* __restrict__ cnt,
                                                    unsigned short* __restrict__ slots,
                                                    const float* __restrict__ x,
                                                    const unsigned short* __restrict__ Wt1,
                                                    unsigned char* __restrict__ H1) {
    __shared__ unsigned short wsh[DIM][136];   // 272B row stride (gemm blocks only)
    const int tid = threadIdx.x;

    if (blockIdx.x >= GEMM1_BLOCKS) {
        // ---------------- adjacency fill: 8 edges/thread (2x int4) ----------------
        int e0 = (((blockIdx.x - GEMM1_BLOCKS) * 512) + tid) * 8;
        #pragma unroll
        for (int h = 0; h < 2; h++) {
            int e = e0 + h * 4;
            if (e + 3 < N_EDGES) {
                int4 s4 = *reinterpret_cast<const int4*>(src + e);
                int4 d4 = *reinterpret_cast<const int4*>(dst + e);
                int p0 = atomicAdd(&cnt[d4.x], 1);
                int p1 = atomicAdd(&cnt[d4.y], 1);
                int p2 = atomicAdd(&cnt[d4.z], 1);
                int p3 = atomicAdd(&cnt[d4.w], 1);
                if (p0 < SLOTS) slots[d4.x * SLOTS + p0] = (unsigned short)s4.x;
                if (p1 < SLOTS) slots[d4.y * SLOTS + p1] = (unsigned short)s4.y;
                if (p2 < SLOTS) slots[d4.z * SLOTS + p2] = (unsigned short)s4.z;
                if (p3 < SLOTS) slots[d4.w * SLOTS + p3] = (unsigned short)s4.w;
            } else if (e < N_EDGES) {
                for (int q = e; q < N_EDGES; q++) {
                    int s = src[q], d = dst[q];
                    int p = atomicAdd(&cnt[d], 1);
                    if (p < SLOTS) slots[d * SLOTS + p] = (unsigned short)s;
                }
            }
        }
        return;
    }

    // ---------------- GEMM1 (fp32 A -> fp8 out) ----------------
    #pragma unroll
    for (int i = 0; i < 4; i++) {
        int off = tid * 8 + i * 4096;
        int r = off >> 7, cc = off & 127;
        u16x8 v = *reinterpret_cast<const u16x8*>(Wt1 + off);
        *reinterpret_cast<u16x8*>(&wsh[r][cc]) = v;
    }
    __syncthreads();

    const int wid  = tid >> 6;
    const int lane = tid & 63;
    const int l15  = lane & 15;
    const int lk   = lane >> 4;
    const int row0 = blockIdx.x * 256 + wid * 32;

    f32x4 acc[2][8];
    #pragma unroll
    for (int a = 0; a < 2; a++)
        #pragma unroll
        for (int n = 0; n < 8; n++) acc[a][n] = (f32x4){0.f, 0.f, 0.f, 0.f};

    const long long r0 = min(row0 + l15,      N_NODES - 1);
    const long long r1 = min(row0 + 16 + l15, N_NODES - 1);

    #pragma unroll
    for (int kk = 0; kk < 4; kk++) {
        const int kb = kk * 32 + lk * 8;
        s16x8 a0, a1;
        const float4 p0 = *reinterpret_cast<const float4*>(x + r0 * DIM + kb);
        const float4 q0 = *reinterpret_cast<const float4*>(x + r0 * DIM + kb + 4);
        const float4 p1 = *reinterpret_cast<const float4*>(x + r1 * DIM + kb);
        const float4 q1 = *reinterpret_cast<const float4*>(x + r1 * DIM + kb + 4);
        a0[0]=(short)f2bf(p0.x); a0[1]=(short)f2bf(p0.y); a0[2]=(short)f2bf(p0.z); a0[3]=(short)f2bf(p0.w);
        a0[4]=(short)f2bf(q0.x); a0[5]=(short)f2bf(q0.y); a0[6]=(short)f2bf(q0.z); a0[7]=(short)f2bf(q0.w);
        a1[0]=(short)f2bf(p1.x); a1[1]=(short)f2bf(p1.y); a1[2]=(short)f2bf(p1.z); a1[3]=(short)f2bf(p1.w);
        a1[4]=(short)f2bf(q1.x); a1[5]=(short)f2bf(q1.y); a1[6]=(short)f2bf(q1.z); a1[7]=(short)f2bf(q1.w);
        #pragma unroll
        for (int n = 0; n < 8; n++) {
            s16x8 b = *reinterpret_cast<const s16x8*>(&wsh[n * 16 + l15][kb]);
            acc[0][n] = __builtin_amdgcn_mfma_f32_16x16x32_bf16(a0, b, acc[0][n], 0, 0, 0);
            acc[1][n] = __builtin_amdgcn_mfma_f32_16x16x32_bf16(a1, b, acc[1][n], 0, 0, 0);
        }
    }

    #pragma unroll
    for (int rh = 0; rh < 2; rh++) {
        #pragma unroll
        for (int j = 0; j < 4; j++) {
            int row = row0 + rh * 16 + lk * 4 + j;
            if (row < N_NODES) {
                #pragma unroll
                for (int n = 0; n < 8; n++)
                    H1[(long long)row * DIM + n * 16 + l15] = f32_to_fp8(acc[rh][n][j]);
            }
        }
    }
}

// ================================================================ shared gather body (16 lanes/node, 4x unroll; fp8 rows)
template<int WITH_BIAS>
__device__ inline void gather_node(const int* __restrict__ cnt,
                                   const unsigned short* __restrict__ slots,
                                   const unsigned char* __restrict__ h8,
                                   const float* __restrict__ bias,
                                   int n, int c, float dn, float* acc) {
    float d2 = dn * dn;
    u8x8 hv = *reinterpret_cast<const u8x8*>(h8 + (size_t)n * DIM + c);
    #pragma unroll
    for (int j = 0; j < 8; j++) acc[j] = fp8_to_f32(hv[j]) * d2 + (WITH_BIAS ? bias[c + j] : 0.f);

    const int m = min(cnt[n], SLOTS);
    const unsigned short* sl = slots + (size_t)n * SLOTS;

    int i = 0;
    for (; i + 3 < m; i += 4) {
        int s0 = sl[i], s1 = sl[i + 1], s2 = sl[i + 2], s3 = sl[i + 3];
        float w0 = rsqrtf((float)cnt[s0] + 1.0f) * dn;
        float w1 = rsqrtf((float)cnt[s1] + 1.0f) * dn;
        float w2 = rsqrtf((float)cnt[s2] + 1.0f) * dn;
        float w3 = rsqrtf((float)cnt[s3] + 1.0f) * dn;
        u8x8 v0 = *reinterpret_cast<const u8x8*>(h8 + (size_t)s0 * DIM + c);
        u8x8 v1 = *reinterpret_cast<const u8x8*>(h8 + (size_t)s1 * DIM + c);
        u8x8 v2 = *reinterpret_cast<const u8x8*>(h8 + (size_t)s2 * DIM + c);
        u8x8 v3 = *reinterpret_cast<const u8x8*>(h8 + (size_t)s3 * DIM + c);
        #pragma unroll
        for (int j = 0; j < 8; j++)
            acc[j] += (fp8_to_f32(v0[j]) * w0 + fp8_to_f32(v1[j]) * w1) +
                      (fp8_to_f32(v2[j]) * w2 + fp8_to_f32(v3[j]) * w3);
    }
    for (; i < m; i++) {
        int s0 = sl[i];
        float w0 = rsqrtf((float)cnt[s0] + 1.0f) * dn;
        u8x8 v0 = *reinterpret_cast<const u8x8*>(h8 + (size_t)s0 * DIM + c);
        #pragma unroll
        for (int j = 0; j < 8; j++) acc[j] += fp8_to_f32(v0[j]) * w0;
    }
}

// ================================================================ pull layer 1 (fp8 in, relu, fp8 out)
__global__ __launch_bounds__(256) void k_pull1(const int* __restrict__ cnt,
                                               const unsigned short* __restrict__ slots,
                                               const unsigned char* __restrict__ h,
                                               const float* __restrict__ bias,
                                               unsigned char* __restrict__ outp) {
    int gid = blockIdx.x * blockDim.x + threadIdx.x;
    int n = gid >> 4;
    if (n >= N_NODES) return;
    int c = (gid & 15) << 3;

    float dn = rsqrtf((float)cnt[n] + 1.0f);
    float acc[8];
    gather_node<1>(cnt, slots, h, bias, n, c, dn, acc);

    u8x8 o;
    #pragma unroll
    for (int j = 0; j < 8; j++) o[j] = f32_to_fp8(fmaxf(acc[j], 0.f));
    *reinterpret_cast<u8x8*>(outp + (size_t)n * DIM + c) = o;
}

// ================================================================ layer-2 gather (over Z1 fp8, no bias/W2) + mean-pool stage 1
__global__ __launch_bounds__(256) void k_pull_pool(const int* __restrict__ cnt,
                                                   const unsigned short* __restrict__ slots,
                                                   const unsigned char* __restrict__ h,
                                                   const int* __restrict__ batch,
                                                   float* __restrict__ pooled) {
    __shared__ float pool_l[2][DIM];
    const int tid  = threadIdx.x;
    const int base = blockIdx.x * 64;
    const int c    = (tid & 15) << 3;

    pool_l[tid >> 7][tid & 127] = 0.f;
    __syncthreads();

    const int gmin = batch[min(base, N_NODES - 1)];

    #pragma unroll
    for (int r = 0; r < 4; r++) {
        int n = base + r * 16 + (tid >> 4);
        bool valid = n < N_NODES;
        int nn = min(n, N_NODES - 1);

        float dn = rsqrtf((float)cnt[nn] + 1.0f);
        float acc[8];
        gather_node<0>(cnt, slots, h, nullptr, nn, c, dn, acc);   // Agg(z1)
        if (!valid) {
            #pragma unroll
            for (int j = 0; j < 8; j++) acc[j] = 0.f;
        }

        const int g = batch[nn];
        const int d = g - gmin;

        if (__all(g == __shfl(g, 0))) {
            #pragma unroll
            for (int j = 0; j < 8; j++) {
                acc[j] += __shfl_xor(acc[j], 16);
                acc[j] += __shfl_xor(acc[j], 32);
            }
            if ((tid & 63) < 16) {
                if (d < 2) {
                    #pragma unroll
                    for (int j = 0; j < 8; j++) atomicAdd(&pool_l[d][c + j], acc[j]);
                } else {
                    #pragma unroll
                    for (int j = 0; j < 8; j++) atomicAdd(&pooled[g * DIM + c + j], acc[j]);
                }
            }
        } else {
            if (d < 2) {
                #pragma unroll
                for (int j = 0; j < 8; j++) atomicAdd(&pool_l[d][c + j], acc[j]);
            } else {
                #pragma unroll
                for (int j = 0; j < 8; j++) atomicAdd(&pooled[g * DIM + c + j], acc[j]);
            }
        }
    }
    __syncthreads();

    const int f = tid & 127;
    if (tid < 128) {
        atomicAdd(&pooled[gmin * DIM + f], pool_l[0][f]);
    } else {
        int last = min(base + 63, N_NODES - 1);
        if (batch[last] > gmin) atomicAdd(&pooled[(gmin + 1) * DIM + f], pool_l[1][f]);
    }
}

// ================================================================ pool stage 2: mean -> @W2+b2 -> @Wlin+blin -> relu (fp32)
__global__ __launch_bounds__(128) void k_pool2(const float* __restrict__ pooledA,
                                               const int* __restrict__ batch,
                                               const float* __restrict__ W2,
                                               const float* __restrict__ b2,
                                               const float* __restrict__ Wlin,
                                               const float* __restrict__ blin,
                                               float* __restrict__ out) {
    int g = blockIdx.x;
    int t = threadIdx.x;
    __shared__ int se[2];
    __shared__ float pa[DIM];
    __shared__ float z[DIM];
    if (t < 2) {
        int target = g + t;
        int lo = 0, hi = N_NODES;
        while (lo < hi) { int mid = (lo + hi) >> 1; if (batch[mid] < target) lo = mid + 1; else hi = mid; }
        se[t] = lo;
    }
    __syncthreads();
    float inv_cnt = 1.0f / fmaxf((float)(se[1] - se[0]), 1.0f);
    pa[t] = pooledA[g * DIM + t] * inv_cnt;
    __syncthreads();
    float acc = b2[t];
    #pragma unroll 8
    for (int k = 0; k < DIM; k++) acc += pa[k] * W2[k * DIM + t];
    z[t] = acc;
    __syncthreads();
    float acc2 = blin[t];
    #pragma unroll 8
    for (int k = 0; k < DIM; k++) acc2 += z[k] * Wlin[k * DIM + t];
    out[g * DIM + t] = fmaxf(acc2, 0.f);
}

// ================================================================ launch
extern "C" void kernel_launch(void* const* d_in, const int* in_sizes, int n_in,
                              void* d_out, int out_size, void* d_ws, size_t ws_size,
                              hipStream_t stream) {
    const float* x          = (const float*)d_in[0];
    const int*   edge_index = (const int*)d_in[1];
    const int*   batch      = (const int*)d_in[2];
    const float* W1         = (const float*)d_in[3];
    const float* b1         = (const float*)d_in[4];
    const float* W2         = (const float*)d_in[5];
    const float* b2         = (const float*)d_in[6];
    const float* Wlin       = (const float*)d_in[7];
    const float* blin       = (const float*)d_in[8];
    float*       out        = (float*)d_out;

    const int* src = edge_index;
    const int* dst = edge_index + N_EDGES;

    char* ws = (char*)d_ws;
    size_t off = 0;
    auto alloc = [&](size_t bytes) { void* p = ws + off; off = (off + bytes + 255) & ~255ULL; return p; };
    int*            cnt    = (int*)            alloc((size_t)N_NODES * 4);
    unsigned short* slots  = (unsigned short*) alloc((size_t)N_NODES * SLOTS * 2);
    float*          pooled = (float*)          alloc((size_t)NUM_GRAPHS * DIM * 4);
    unsigned short* Wt1    = (unsigned short*) alloc((size_t)DIM * DIM * 2);
    unsigned char*  H1     = (unsigned char*)  alloc((size_t)N_NODES * DIM);   // fp8
    unsigned char*  Z1     = (unsigned char*)  alloc((size_t)N_NODES * DIM);   // fp8

    const int pull1Blocks = (N_NODES * 16 + 255) / 256;     // 3125
    const int poolBlocks  = (N_NODES + 63) / 64;            // 782

    // ---- weight prep (W1) + zero cnt/pooled ----
    k_prep_w<<<DIM, DIM, 0, stream>>>(W1, Wt1, cnt, pooled);

    // ---- GEMM1 (fp8 out) || adjacency fill (8 edges/thread) ----
    k_fill_gemm1<<<GEMM1_BLOCKS + FILL_BLOCKS, 512, 0, stream>>>(src, dst, cnt, slots, x, Wt1, H1);

    // ---- layer 1 gather (fp8 in, fp8 out) ----
    k_pull1<<<pull1Blocks, 256, 0, stream>>>(cnt, slots, H1, b1, Z1);

    // ---- layer-2 gather + mean-pool stage 1 (W2 deferred to pool2) ----
    k_pull_pool<<<poolBlocks, 256, 0, stream>>>(cnt, slots, Z1, batch, pooled);

    // ---- pool stage 2: mean, @W2+b2, @Wlin+blin, relu ----
    k_pool2<<<NUM_GRAPHS, 128, 0, stream>>>(pooled, batch, W2, b2, Wlin, blin, out);
}

// Round 17
// 107.784 us; speedup vs baseline: 1.0705x; 1.0705x over previous
//
#include <hip/hip_runtime.h>
#include <string.h>

#define N_NODES   50000
#define N_EDGES   640000
#define DIM       128
#define NUM_GRAPHS 64
#define SLOTS     64   // max in-degree slot capacity; P(deg>=64 | lambda=12.8) ~ 3e-23/node
#define GEMM1_BLOCKS 196   // ceil(N_NODES/256)
#define FILL_BLOCKS  157   // ceil(N_EDGES / (512*8))

typedef __attribute__((ext_vector_type(8))) short          s16x8;
typedef __attribute__((ext_vector_type(8))) unsigned short u16x8;
typedef __attribute__((ext_vector_type(8))) unsigned char  u8x8;
typedef __attribute__((ext_vector_type(4))) float          f32x4;
typedef __attribute__((ext_vector_type(2))) float          f32x2;

__device__ inline float bf2f(unsigned short u) {
    unsigned v = ((unsigned)u) << 16;
    float f;
    __builtin_memcpy(&f, &v, 4);
    return f;
}
__device__ inline unsigned short f2bf(float f) {
    unsigned u;
    __builtin_memcpy(&u, &f, 4);
    u = (u + 0x7fffu + ((u >> 16) & 1u)) >> 16;   // RNE
    return (unsigned short)u;
}

// ---------------- fp8 e4m3 (OCP) helpers ----------------
__device__ inline float fp8_to_f32(unsigned char b) {
#if defined(__has_builtin)
#if __has_builtin(__builtin_amdgcn_cvt_f32_fp8)
    return __builtin_amdgcn_cvt_f32_fp8((int)b, 0);
#else
    unsigned s = (b >> 7) & 1u, em = b & 0x7fu;
    unsigned bits = (s << 31) | (em << 20);
    float x;
    __builtin_memcpy(&x, &bits, 4);
    return x * 0x1.0p+120f;
#endif
#else
    unsigned s = (b >> 7) & 1u, em = b & 0x7fu;
    unsigned bits = (s << 31) | (em << 20);
    float x;
    __builtin_memcpy(&x, &bits, 4);
    return x * 0x1.0p+120f;
#endif
}

// decode 8 fp8 (two u32s) -> 8 f32, packed 2-at-a-time where available
__device__ inline void fp8x8_dec(uint2 rv, float* out) {
#if defined(__has_builtin)
#if __has_builtin(__builtin_amdgcn_cvt_pk_f32_fp8)
    f32x2 a = __builtin_amdgcn_cvt_pk_f32_fp8((int)rv.x, false);
    f32x2 b = __builtin_amdgcn_cvt_pk_f32_fp8((int)rv.x, true);
    f32x2 c = __builtin_amdgcn_cvt_pk_f32_fp8((int)rv.y, false);
    f32x2 d = __builtin_amdgcn_cvt_pk_f32_fp8((int)rv.y, true);
    out[0] = a[0]; out[1] = a[1]; out[2] = b[0]; out[3] = b[1];
    out[4] = c[0]; out[5] = c[1]; out[6] = d[0]; out[7] = d[1];
#define FP8_PK_DEC 1
#endif
#endif
#ifndef FP8_PK_DEC
    unsigned char by[8];
    __builtin_memcpy(by, &rv, 8);
    #pragma unroll
    for (int j = 0; j < 8; j++) out[j] = fp8_to_f32(by[j]);
#endif
}

__device__ inline unsigned char f32_to_fp8(float v) {
#if defined(__has_builtin)
#if __has_builtin(__builtin_amdgcn_cvt_pk_fp8_f32)
    int r = __builtin_amdgcn_cvt_pk_fp8_f32(v, v, 0, false);
    return (unsigned char)(r & 0xff);
#define FP8_HW_ENC 1
#endif
#endif
#ifndef FP8_HW_ENC
    unsigned bits;
    __builtin_memcpy(&bits, &v, 4);
    unsigned s = bits >> 31;
    float av = fabsf(v);
    if (av < 0x1.0p-10f) return (unsigned char)(s << 7);
    if (av >= 448.f)     return (unsigned char)((s << 7) | 0x7E);
    int e = (int)((bits >> 23) & 0xFF) - 127;
    unsigned m = bits & 0x7FFFFF;
    if (e >= -6) {
        unsigned r = m + 0x0FFFFF + ((m >> 20) & 1);
        unsigned mm = r >> 20;
        unsigned ee = (unsigned)(e + 7);
        if (mm >= 8) { mm = 0; ee += 1; }
        if (ee >= 16) return (unsigned char)((s << 7) | 0x7E);
        return (unsigned char)((s << 7) | (ee << 3) | mm);
    } else {
        float scaled = av * 0x1.0p+9f;
        int d = (int)(scaled + 0.5f);
        if (d >= 8) return (unsigned char)((s << 7) | (1u << 3));
        return (unsigned char)((s << 7) | (unsigned)d);
    }
#endif
}

// ================================================================ weight prep (W1 only) + zeroing
__global__ __launch_bounds__(128) void k_prep_w(const float* __restrict__ W1,
                                                unsigned short* __restrict__ Wt1,
                                                int* __restrict__ cnt,
                                                float* __restrict__ pooled) {
    int k = blockIdx.x;            // 0..127
    int n = threadIdx.x;
    Wt1[n * DIM + k] = f2bf(W1[k * DIM + n]);

    int gid = blockIdx.x * 128 + threadIdx.x;          // 16384 threads
    for (int i = gid; i < N_NODES; i += 16384) cnt[i] = 0;
    if (gid < NUM_GRAPHS * DIM) pooled[gid] = 0.f;
}

// ================================================================ GEMM1 || fill_slots (block-range fused)
// blocks [0, GEMM1_BLOCKS): H1 = fp8(x @ W1); rest: 8-edge/thread slotted fill
__global__ __launch_bounds__(512) void k_fill_gemm1(const int* __restrict__ src,
                                                    const int* __restrict__ dst,
                                                    int* __restrict__ cnt,
                                                    unsigned short* __restrict__ slots,
                                                    const float* __restrict__ x,
                                                    const unsigned short* __restrict__ Wt1,
                                                    unsigned char* __restrict__ H1) {
    __shared__ unsigned short wsh[DIM][136];   // 272B row stride (gemm blocks only)
    const int tid = threadIdx.x;

    if (blockIdx.x >= GEMM1_BLOCKS) {
        // ---------------- adjacency fill: 8 edges/thread (2x int4) ----------------
        int e0 = (((blockIdx.x - GEMM1_BLOCKS) * 512) + tid) * 8;
        #pragma unroll
        for (int h = 0; h < 2; h++) {
            int e = e0 + h * 4;
            if (e + 3 < N_EDGES) {
                int4 s4 = *reinterpret_cast<const int4*>(src + e);
                int4 d4 = *reinterpret_cast<const int4*>(dst + e);
                int p0 = atomicAdd(&cnt[d4.x], 1);
                int p1 = atomicAdd(&cnt[d4.y], 1);
                int p2 = atomicAdd(&cnt[d4.z], 1);
                int p3 = atomicAdd(&cnt[d4.w], 1);
                if (p0 < SLOTS) slots[d4.x * SLOTS + p0] = (unsigned short)s4.x;
                if (p1 < SLOTS) slots[d4.y * SLOTS + p1] = (unsigned short)s4.y;
                if (p2 < SLOTS) slots[d4.z * SLOTS + p2] = (unsigned short)s4.z;
                if (p3 < SLOTS) slots[d4.w * SLOTS + p3] = (unsigned short)s4.w;
            } else if (e < N_EDGES) {
                for (int q = e; q < N_EDGES; q++) {
                    int s = src[q], d = dst[q];
                    int p = atomicAdd(&cnt[d], 1);
                    if (p < SLOTS) slots[d * SLOTS + p] = (unsigned short)s;
                }
            }
        }
        return;
    }

    // ---------------- GEMM1 (fp32 A -> fp8 out) ----------------
    #pragma unroll
    for (int i = 0; i < 4; i++) {
        int off = tid * 8 + i * 4096;
        int r = off >> 7, cc = off & 127;
        u16x8 v = *reinterpret_cast<const u16x8*>(Wt1 + off);
        *reinterpret_cast<u16x8*>(&wsh[r][cc]) = v;
    }
    __syncthreads();

    const int wid  = tid >> 6;
    const int lane = tid & 63;
    const int l15  = lane & 15;
    const int lk   = lane >> 4;
    const int row0 = blockIdx.x * 256 + wid * 32;

    f32x4 acc[2][8];
    #pragma unroll
    for (int a = 0; a < 2; a++)
        #pragma unroll
        for (int n = 0; n < 8; n++) acc[a][n] = (f32x4){0.f, 0.f, 0.f, 0.f};

    const long long r0 = min(row0 + l15,      N_NODES - 1);
    const long long r1 = min(row0 + 16 + l15, N_NODES - 1);

    #pragma unroll
    for (int kk = 0; kk < 4; kk++) {
        const int kb = kk * 32 + lk * 8;
        s16x8 a0, a1;
        const float4 p0 = *reinterpret_cast<const float4*>(x + r0 * DIM + kb);
        const float4 q0 = *reinterpret_cast<const float4*>(x + r0 * DIM + kb + 4);
        const float4 p1 = *reinterpret_cast<const float4*>(x + r1 * DIM + kb);
        const float4 q1 = *reinterpret_cast<const float4*>(x + r1 * DIM + kb + 4);
        a0[0]=(short)f2bf(p0.x); a0[1]=(short)f2bf(p0.y); a0[2]=(short)f2bf(p0.z); a0[3]=(short)f2bf(p0.w);
        a0[4]=(short)f2bf(q0.x); a0[5]=(short)f2bf(q0.y); a0[6]=(short)f2bf(q0.z); a0[7]=(short)f2bf(q0.w);
        a1[0]=(short)f2bf(p1.x); a1[1]=(short)f2bf(p1.y); a1[2]=(short)f2bf(p1.z); a1[3]=(short)f2bf(p1.w);
        a1[4]=(short)f2bf(q1.x); a1[5]=(short)f2bf(q1.y); a1[6]=(short)f2bf(q1.z); a1[7]=(short)f2bf(q1.w);
        #pragma unroll
        for (int n = 0; n < 8; n++) {
            s16x8 b = *reinterpret_cast<const s16x8*>(&wsh[n * 16 + l15][kb]);
            acc[0][n] = __builtin_amdgcn_mfma_f32_16x16x32_bf16(a0, b, acc[0][n], 0, 0, 0);
            acc[1][n] = __builtin_amdgcn_mfma_f32_16x16x32_bf16(a1, b, acc[1][n], 0, 0, 0);
        }
    }

    #pragma unroll
    for (int rh = 0; rh < 2; rh++) {
        #pragma unroll
        for (int j = 0; j < 4; j++) {
            int row = row0 + rh * 16 + lk * 4 + j;
            if (row < N_NODES) {
                #pragma unroll
                for (int n = 0; n < 8; n++)
                    H1[(long long)row * DIM + n * 16 + l15] = f32_to_fp8(acc[rh][n][j]);
            }
        }
    }
}

// ================================================================ dinv precompute (after fill)
__global__ __launch_bounds__(256) void k_dinv(const int* __restrict__ cnt,
                                              float* __restrict__ dinv) {
    int n = blockIdx.x * blockDim.x + threadIdx.x;
    if (n < N_NODES) dinv[n] = rsqrtf((float)cnt[n] + 1.0f);
}

// ================================================================ shared gather body (16 lanes/node; fp8 rows; dinv precomputed)
template<int WITH_BIAS>
__device__ inline void gather_node(const int* __restrict__ cnt,
                                   const float* __restrict__ dinv,
                                   const unsigned short* __restrict__ slots,
                                   const unsigned char* __restrict__ h8,
                                   const float* __restrict__ bias,
                                   int n, int c, float dn, float* acc) {
    float d2 = dn * dn;
    float self[8];
    fp8x8_dec(*reinterpret_cast<const uint2*>(h8 + (size_t)n * DIM + c), self);
    #pragma unroll
    for (int j = 0; j < 8; j++) acc[j] = self[j] * d2 + (WITH_BIAS ? bias[c + j] : 0.f);

    const int m = min(cnt[n], SLOTS);
    const unsigned short* sl = slots + (size_t)n * SLOTS;

    int i = 0;
    for (; i + 3 < m; i += 4) {
        ushort4 sv = *reinterpret_cast<const ushort4*>(sl + i);   // 8B slot read
        int s0 = sv.x, s1 = sv.y, s2 = sv.z, s3 = sv.w;
        float w0 = dinv[s0] * dn;
        float w1 = dinv[s1] * dn;
        float w2 = dinv[s2] * dn;
        float w3 = dinv[s3] * dn;
        float v0[8], v1[8], v2[8], v3[8];
        fp8x8_dec(*reinterpret_cast<const uint2*>(h8 + (size_t)s0 * DIM + c), v0);
        fp8x8_dec(*reinterpret_cast<const uint2*>(h8 + (size_t)s1 * DIM + c), v1);
        fp8x8_dec(*reinterpret_cast<const uint2*>(h8 + (size_t)s2 * DIM + c), v2);
        fp8x8_dec(*reinterpret_cast<const uint2*>(h8 + (size_t)s3 * DIM + c), v3);
        #pragma unroll
        for (int j = 0; j < 8; j++)
            acc[j] += (v0[j] * w0 + v1[j] * w1) + (v2[j] * w2 + v3[j] * w3);
    }
    for (; i < m; i++) {
        int s0 = sl[i];
        float w0 = dinv[s0] * dn;
        float v0[8];
        fp8x8_dec(*reinterpret_cast<const uint2*>(h8 + (size_t)s0 * DIM + c), v0);
        #pragma unroll
        for (int j = 0; j < 8; j++) acc[j] += v0[j] * w0;
    }
}

// ================================================================ pull layer 1 (fp8 in, relu, fp8 out)
__global__ __launch_bounds__(256) void k_pull1(const int* __restrict__ cnt,
                                               const float* __restrict__ dinv,
                                               const unsigned short* __restrict__ slots,
                                               const unsigned char* __restrict__ h,
                                               const float* __restrict__ bias,
                                               unsigned char* __restrict__ outp) {
    int gid = blockIdx.x * blockDim.x + threadIdx.x;
    int n = gid >> 4;
    if (n >= N_NODES) return;
    int c = (gid & 15) << 3;

    float dn = dinv[n];
    float acc[8];
    gather_node<1>(cnt, dinv, slots, h, bias, n, c, dn, acc);

    u8x8 o;
    #pragma unroll
    for (int j = 0; j < 8; j++) o[j] = f32_to_fp8(fmaxf(acc[j], 0.f));
    *reinterpret_cast<u8x8*>(outp + (size_t)n * DIM + c) = o;
}

// ================================================================ layer-2 gather (over Z1 fp8, no bias/W2) + mean-pool stage 1
__global__ __launch_bounds__(256) void k_pull_pool(const int* __restrict__ cnt,
                                                   const float* __restrict__ dinv,
                                                   const unsigned short* __restrict__ slots,
                                                   const unsigned char* __restrict__ h,
                                                   const int* __restrict__ batch,
                                                   float* __restrict__ pooled) {
    __shared__ float pool_l[2][DIM];
    const int tid  = threadIdx.x;
    const int base = blockIdx.x * 64;
    const int c    = (tid & 15) << 3;

    pool_l[tid >> 7][tid & 127] = 0.f;
    __syncthreads();

    const int gmin = batch[min(base, N_NODES - 1)];

    #pragma unroll
    for (int r = 0; r < 4; r++) {
        int n = base + r * 16 + (tid >> 4);
        bool valid = n < N_NODES;
        int nn = min(n, N_NODES - 1);

        float dn = dinv[nn];
        float acc[8];
        gather_node<0>(cnt, dinv, slots, h, nullptr, nn, c, dn, acc);   // Agg(z1)
        if (!valid) {
            #pragma unroll
            for (int j = 0; j < 8; j++) acc[j] = 0.f;
        }

        const int g = batch[nn];
        const int d = g - gmin;

        if (__all(g == __shfl(g, 0))) {
            #pragma unroll
            for (int j = 0; j < 8; j++) {
                acc[j] += __shfl_xor(acc[j], 16);
                acc[j] += __shfl_xor(acc[j], 32);
            }
            if ((tid & 63) < 16) {
                if (d < 2) {
                    #pragma unroll
                    for (int j = 0; j < 8; j++) atomicAdd(&pool_l[d][c + j], acc[j]);
                } else {
                    #pragma unroll
                    for (int j = 0; j < 8; j++) atomicAdd(&pooled[g * DIM + c + j], acc[j]);
                }
            }
        } else {
            if (d < 2) {
                #pragma unroll
                for (int j = 0; j < 8; j++) atomicAdd(&pool_l[d][c + j], acc[j]);
            } else {
                #pragma unroll
                for (int j = 0; j < 8; j++) atomicAdd(&pooled[g * DIM + c + j], acc[j]);
            }
        }
    }
    __syncthreads();

    const int f = tid & 127;
    if (tid < 128) {
        atomicAdd(&pooled[gmin * DIM + f], pool_l[0][f]);
    } else {
        int last = min(base + 63, N_NODES - 1);
        if (batch[last] > gmin) atomicAdd(&pooled[(gmin + 1) * DIM + f], pool_l[1][f]);
    }
}

// ================================================================ pool stage 2: mean -> @W2+b2 -> @Wlin+blin -> relu (fp32)
__global__ __launch_bounds__(128) void k_pool2(const float* __restrict__ pooledA,
                                               const int* __restrict__ batch,
                                               const float* __restrict__ W2,
                                               const float* __restrict__ b2,
                                               const float* __restrict__ Wlin,
                                               const float* __restrict__ blin,
                                               float* __restrict__ out) {
    int g = blockIdx.x;
    int t = threadIdx.x;
    __shared__ int se[2];
    __shared__ float pa[DIM];
    __shared__ float z[DIM];
    if (t < 2) {
        int target = g + t;
        int lo = 0, hi = N_NODES;
        while (lo < hi) { int mid = (lo + hi) >> 1; if (batch[mid] < target) lo = mid + 1; else hi = mid; }
        se[t] = lo;
    }
    __syncthreads();
    float inv_cnt = 1.0f / fmaxf((float)(se[1] - se[0]), 1.0f);
    pa[t] = pooledA[g * DIM + t] * inv_cnt;
    __syncthreads();
    float acc = b2[t];
    #pragma unroll 8
    for (int k = 0; k < DIM; k++) acc += pa[k] * W2[k * DIM + t];
    z[t] = acc;
    __syncthreads();
    float acc2 = blin[t];
    #pragma unroll 8
    for (int k = 0; k < DIM; k++) acc2 += z[k] * Wlin[k * DIM + t];
    out[g * DIM + t] = fmaxf(acc2, 0.f);
}

// ================================================================ launch
extern "C" void kernel_launch(void* const* d_in, const int* in_sizes, int n_in,
                              void* d_out, int out_size, void* d_ws, size_t ws_size,
                              hipStream_t stream) {
    const float* x          = (const float*)d_in[0];
    const int*   edge_index = (const int*)d_in[1];
    const int*   batch      = (const int*)d_in[2];
    const float* W1         = (const float*)d_in[3];
    const float* b1         = (const float*)d_in[4];
    const float* W2         = (const float*)d_in[5];
    const float* b2         = (const float*)d_in[6];
    const float* Wlin       = (const float*)d_in[7];
    const float* blin       = (const float*)d_in[8];
    float*       out        = (float*)d_out;

    const int* src = edge_index;
    const int* dst = edge_index + N_EDGES;

    char* ws = (char*)d_ws;
    size_t off = 0;
    auto alloc = [&](size_t bytes) { void* p = ws + off; off = (off + bytes + 255) & ~255ULL; return p; };
    int*            cnt    = (int*)            alloc((size_t)N_NODES * 4);
    float*          dinv   = (float*)          alloc((size_t)N_NODES * 4);
    unsigned short* slots  = (unsigned short*) alloc((size_t)N_NODES * SLOTS * 2);
    float*          pooled = (float*)          alloc((size_t)NUM_GRAPHS * DIM * 4);
    unsigned short* Wt1    = (unsigned short*) alloc((size_t)DIM * DIM * 2);
    unsigned char*  H1     = (unsigned char*)  alloc((size_t)N_NODES * DIM);   // fp8
    unsigned char*  Z1     = (unsigned char*)  alloc((size_t)N_NODES * DIM);   // fp8

    const int nodeBlocks  = (N_NODES + 255) / 256;          // 196
    const int pull1Blocks = (N_NODES * 16 + 255) / 256;     // 3125
    const int poolBlocks  = (N_NODES + 63) / 64;            // 782

    // ---- weight prep (W1) + zero cnt/pooled ----
    k_prep_w<<<DIM, DIM, 0, stream>>>(W1, Wt1, cnt, pooled);

    // ---- GEMM1 (fp8 out) || adjacency fill (8 edges/thread) ----
    k_fill_gemm1<<<GEMM1_BLOCKS + FILL_BLOCKS, 512, 0, stream>>>(src, dst, cnt, slots, x, Wt1, H1);

    // ---- dinv (needs complete cnt) ----
    k_dinv<<<nodeBlocks, 256, 0, stream>>>(cnt, dinv);

    // ---- layer 1 gather (fp8 in, fp8 out) ----
    k_pull1<<<pull1Blocks, 256, 0, stream>>>(cnt, dinv, slots, H1, b1, Z1);

    // ---- layer-2 gather + mean-pool stage 1 (W2 deferred to pool2) ----
    k_pull_pool<<<poolBlocks, 256, 0, stream>>>(cnt, dinv, slots, Z1, batch, pooled);

    // ---- pool stage 2: mean, @W2+b2, @Wlin+blin, relu ----
    k_pool2<<<NUM_GRAPHS, 128, 0, stream>>>(pooled, batch, W2, b2, Wlin, blin, out);
}

// Round 18
// 107.178 us; speedup vs baseline: 1.0766x; 1.0057x over previous
//
#include <hip/hip_runtime.h>
#include <string.h>

#define N_NODES   50000
#define N_EDGES   640000
#define DIM       128
#define NUM_GRAPHS 64
#define SLOTS     64   // max in-degree slot capacity; P(deg>=64 | lambda=12.8) ~ 3e-23/node
#define GEMM1_BLOCKS 196   // ceil(N_NODES/256)
#define FILL_BLOCKS  157   // ceil(N_EDGES / (512*8))

typedef __attribute__((ext_vector_type(8))) short          s16x8;
typedef __attribute__((ext_vector_type(8))) unsigned short u16x8;
typedef __attribute__((ext_vector_type(8))) unsigned char  u8x8;
typedef __attribute__((ext_vector_type(4))) float          f32x4;
typedef __attribute__((ext_vector_type(2))) float          f32x2;

__device__ inline float bf2f(unsigned short u) {
    unsigned v = ((unsigned)u) << 16;
    float f;
    __builtin_memcpy(&f, &v, 4);
    return f;
}
__device__ inline unsigned short f2bf(float f) {
    unsigned u;
    __builtin_memcpy(&u, &f, 4);
    u = (u + 0x7fffu + ((u >> 16) & 1u)) >> 16;   // RNE
    return (unsigned short)u;
}

// ---------------- fp8 e4m3 (OCP) helpers ----------------
__device__ inline float fp8_to_f32(unsigned char b) {
#if defined(__has_builtin)
#if __has_builtin(__builtin_amdgcn_cvt_f32_fp8)
    return __builtin_amdgcn_cvt_f32_fp8((int)b, 0);
#else
    unsigned s = (b >> 7) & 1u, em = b & 0x7fu;
    unsigned bits = (s << 31) | (em << 20);
    float x;
    __builtin_memcpy(&x, &bits, 4);
    return x * 0x1.0p+120f;
#endif
#else
    unsigned s = (b >> 7) & 1u, em = b & 0x7fu;
    unsigned bits = (s << 31) | (em << 20);
    float x;
    __builtin_memcpy(&x, &bits, 4);
    return x * 0x1.0p+120f;
#endif
}

// decode 8 fp8 (two u32s) -> 8 f32, packed 2-at-a-time where available
__device__ inline void fp8x8_dec(uint2 rv, float* out) {
#if defined(__has_builtin)
#if __has_builtin(__builtin_amdgcn_cvt_pk_f32_fp8)
    f32x2 a = __builtin_amdgcn_cvt_pk_f32_fp8((int)rv.x, false);
    f32x2 b = __builtin_amdgcn_cvt_pk_f32_fp8((int)rv.x, true);
    f32x2 c = __builtin_amdgcn_cvt_pk_f32_fp8((int)rv.y, false);
    f32x2 d = __builtin_amdgcn_cvt_pk_f32_fp8((int)rv.y, true);
    out[0] = a[0]; out[1] = a[1]; out[2] = b[0]; out[3] = b[1];
    out[4] = c[0]; out[5] = c[1]; out[6] = d[0]; out[7] = d[1];
#define FP8_PK_DEC 1
#endif
#endif
#ifndef FP8_PK_DEC
    unsigned char by[8];
    __builtin_memcpy(by, &rv, 8);
    #pragma unroll
    for (int j = 0; j < 8; j++) out[j] = fp8_to_f32(by[j]);
#endif
}

__device__ inline unsigned char f32_to_fp8(float v) {
#if defined(__has_builtin)
#if __has_builtin(__builtin_amdgcn_cvt_pk_fp8_f32)
    int r = __builtin_amdgcn_cvt_pk_fp8_f32(v, v, 0, false);
    return (unsigned char)(r & 0xff);
#define FP8_HW_ENC 1
#endif
#endif
#ifndef FP8_HW_ENC
    unsigned bits;
    __builtin_memcpy(&bits, &v, 4);
    unsigned s = bits >> 31;
    float av = fabsf(v);
    if (av < 0x1.0p-10f) return (unsigned char)(s << 7);
    if (av >= 448.f)     return (unsigned char)((s << 7) | 0x7E);
    int e = (int)((bits >> 23) & 0xFF) - 127;
    unsigned m = bits & 0x7FFFFF;
    if (e >= -6) {
        unsigned r = m + 0x0FFFFF + ((m >> 20) & 1);
        unsigned mm = r >> 20;
        unsigned ee = (unsigned)(e + 7);
        if (mm >= 8) { mm = 0; ee += 1; }
        if (ee >= 16) return (unsigned char)((s << 7) | 0x7E);
        return (unsigned char)((s << 7) | (ee << 3) | mm);
    } else {
        float scaled = av * 0x1.0p+9f;
        int d = (int)(scaled + 0.5f);
        if (d >= 8) return (unsigned char)((s << 7) | (1u << 3));
        return (unsigned char)((s << 7) | (unsigned)d);
    }
#endif
}

// ================================================================ weight prep (W1 only) + zeroing
__global__ __launch_bounds__(128) void k_prep_w(const float* __restrict__ W1,
                                                unsigned short* __restrict__ Wt1,
                                                int* __restrict__ cnt,
                                                float* __restrict__ pooled) {
    int k = blockIdx.x;            // 0..127
    int n = threadIdx.x;
    Wt1[n * DIM + k] = f2bf(W1[k * DIM + n]);

    int gid = blockIdx.x * 128 + threadIdx.x;          // 16384 threads
    for (int i = gid; i < N_NODES; i += 16384) cnt[i] = 0;
    if (gid < NUM_GRAPHS * DIM) pooled[gid] = 0.f;
}

// ================================================================ GEMM1 || fill_slots (block-range fused)
// blocks [0, GEMM1_BLOCKS): H1 = fp8(x @ W1); rest: 8-edge/thread slotted fill
__global__ __launch_bounds__(512) void k_fill_gemm1(const int* __restrict__ src,
                                                    const int* __restrict__ dst,
                                                    int* __restrict__ cnt,
                                                    unsigned short* __restrict__ slots,
                                                    const float* __restrict__ x,
                                                    const unsigned short* __restrict__ Wt1,
                                                    unsigned char* __restrict__ H1) {
    __shared__ unsigned short wsh[DIM][136];   // 272B row stride (gemm blocks only)
    const int tid = threadIdx.x;

    if (blockIdx.x >= GEMM1_BLOCKS) {
        // ---------------- adjacency fill: 8 edges/thread (2x int4) ----------------
        int e0 = (((blockIdx.x - GEMM1_BLOCKS) * 512) + tid) * 8;
        #pragma unroll
        for (int h = 0; h < 2; h++) {
            int e = e0 + h * 4;
            if (e + 3 < N_EDGES) {
                int4 s4 = *reinterpret_cast<const int4*>(src + e);
                int4 d4 = *reinterpret_cast<const int4*>(dst + e);
                int p0 = atomicAdd(&cnt[d4.x], 1);
                int p1 = atomicAdd(&cnt[d4.y], 1);
                int p2 = atomicAdd(&cnt[d4.z], 1);
                int p3 = atomicAdd(&cnt[d4.w], 1);
                if (p0 < SLOTS) slots[d4.x * SLOTS + p0] = (unsigned short)s4.x;
                if (p1 < SLOTS) slots[d4.y * SLOTS + p1] = (unsigned short)s4.y;
                if (p2 < SLOTS) slots[d4.z * SLOTS + p2] = (unsigned short)s4.z;
                if (p3 < SLOTS) slots[d4.w * SLOTS + p3] = (unsigned short)s4.w;
            } else if (e < N_EDGES) {
                for (int q = e; q < N_EDGES; q++) {
                    int s = src[q], d = dst[q];
                    int p = atomicAdd(&cnt[d], 1);
                    if (p < SLOTS) slots[d * SLOTS + p] = (unsigned short)s;
                }
            }
        }
        return;
    }

    // ---------------- GEMM1 (fp32 A -> fp8 out) ----------------
    #pragma unroll
    for (int i = 0; i < 4; i++) {
        int off = tid * 8 + i * 4096;
        int r = off >> 7, cc = off & 127;
        u16x8 v = *reinterpret_cast<const u16x8*>(Wt1 + off);
        *reinterpret_cast<u16x8*>(&wsh[r][cc]) = v;
    }
    __syncthreads();

    const int wid  = tid >> 6;
    const int lane = tid & 63;
    const int l15  = lane & 15;
    const int lk   = lane >> 4;
    const int row0 = blockIdx.x * 256 + wid * 32;

    f32x4 acc[2][8];
    #pragma unroll
    for (int a = 0; a < 2; a++)
        #pragma unroll
        for (int n = 0; n < 8; n++) acc[a][n] = (f32x4){0.f, 0.f, 0.f, 0.f};

    const long long r0 = min(row0 + l15,      N_NODES - 1);
    const long long r1 = min(row0 + 16 + l15, N_NODES - 1);

    #pragma unroll
    for (int kk = 0; kk < 4; kk++) {
        const int kb = kk * 32 + lk * 8;
        s16x8 a0, a1;
        const float4 p0 = *reinterpret_cast<const float4*>(x + r0 * DIM + kb);
        const float4 q0 = *reinterpret_cast<const float4*>(x + r0 * DIM + kb + 4);
        const float4 p1 = *reinterpret_cast<const float4*>(x + r1 * DIM + kb);
        const float4 q1 = *reinterpret_cast<const float4*>(x + r1 * DIM + kb + 4);
        a0[0]=(short)f2bf(p0.x); a0[1]=(short)f2bf(p0.y); a0[2]=(short)f2bf(p0.z); a0[3]=(short)f2bf(p0.w);
        a0[4]=(short)f2bf(q0.x); a0[5]=(short)f2bf(q0.y); a0[6]=(short)f2bf(q0.z); a0[7]=(short)f2bf(q0.w);
        a1[0]=(short)f2bf(p1.x); a1[1]=(short)f2bf(p1.y); a1[2]=(short)f2bf(p1.z); a1[3]=(short)f2bf(p1.w);
        a1[4]=(short)f2bf(q1.x); a1[5]=(short)f2bf(q1.y); a1[6]=(short)f2bf(q1.z); a1[7]=(short)f2bf(q1.w);
        #pragma unroll
        for (int n = 0; n < 8; n++) {
            s16x8 b = *reinterpret_cast<const s16x8*>(&wsh[n * 16 + l15][kb]);
            acc[0][n] = __builtin_amdgcn_mfma_f32_16x16x32_bf16(a0, b, acc[0][n], 0, 0, 0);
            acc[1][n] = __builtin_amdgcn_mfma_f32_16x16x32_bf16(a1, b, acc[1][n], 0, 0, 0);
        }
    }

    #pragma unroll
    for (int rh = 0; rh < 2; rh++) {
        #pragma unroll
        for (int j = 0; j < 4; j++) {
            int row = row0 + rh * 16 + lk * 4 + j;
            if (row < N_NODES) {
                #pragma unroll
                for (int n = 0; n < 8; n++)
                    H1[(long long)row * DIM + n * 16 + l15] = f32_to_fp8(acc[rh][n][j]);
            }
        }
    }
}

// ================================================================ dinv + pre-scale H1 by dinv (in place)
// H1'[n][:] = fp8( dec(H1[n][:]) * dinv[n] ) -> gather becomes a pure row-sum.
__global__ __launch_bounds__(256) void k_scale(const int* __restrict__ cnt,
                                               float* __restrict__ dinv,
                                               unsigned char* __restrict__ H1) {
    int gid = blockIdx.x * blockDim.x + threadIdx.x;
    int n = gid >> 4;
    if (n >= N_NODES) return;
    int c = (gid & 15) << 3;

    float dn = rsqrtf((float)cnt[n] + 1.0f);
    if ((gid & 15) == 0) dinv[n] = dn;

    float v[8];
    fp8x8_dec(*reinterpret_cast<const uint2*>(H1 + (size_t)n * DIM + c), v);
    u8x8 o;
    #pragma unroll
    for (int j = 0; j < 8; j++) o[j] = f32_to_fp8(v[j] * dn);
    *reinterpret_cast<u8x8*>(H1 + (size_t)n * DIM + c) = o;
}

// ================================================================ gather = pure row-sum over pre-scaled rows
// acc = row[n] + sum_{s in N(n)} row[s]   (no dinv loads, no multiplies)
__device__ inline void gather_sum(const int* __restrict__ cnt,
                                  const unsigned short* __restrict__ slots,
                                  const unsigned char* __restrict__ h8,
                                  int n, int c, float* acc) {
    fp8x8_dec(*reinterpret_cast<const uint2*>(h8 + (size_t)n * DIM + c), acc);  // self (weight 1)

    const int m = min(cnt[n], SLOTS);
    const unsigned short* sl = slots + (size_t)n * SLOTS;

    int i = 0;
    for (; i + 3 < m; i += 4) {
        ushort4 sv = *reinterpret_cast<const ushort4*>(sl + i);   // 8B slot read
        float v0[8], v1[8], v2[8], v3[8];
        fp8x8_dec(*reinterpret_cast<const uint2*>(h8 + (size_t)sv.x * DIM + c), v0);
        fp8x8_dec(*reinterpret_cast<const uint2*>(h8 + (size_t)sv.y * DIM + c), v1);
        fp8x8_dec(*reinterpret_cast<const uint2*>(h8 + (size_t)sv.z * DIM + c), v2);
        fp8x8_dec(*reinterpret_cast<const uint2*>(h8 + (size_t)sv.w * DIM + c), v3);
        #pragma unroll
        for (int j = 0; j < 8; j++)
            acc[j] += (v0[j] + v1[j]) + (v2[j] + v3[j]);
    }
    for (; i < m; i++) {
        float v0[8];
        fp8x8_dec(*reinterpret_cast<const uint2*>(h8 + (size_t)sl[i] * DIM + c), v0);
        #pragma unroll
        for (int j = 0; j < 8; j++) acc[j] += v0[j];
    }
}

// ================================================================ pull layer 1
// z1 = relu(dinv[n]*sum + b); store Z1' = fp8(z1 * dinv[n])  (pre-scaled for layer 2)
__global__ __launch_bounds__(256) void k_pull1(const int* __restrict__ cnt,
                                               const float* __restrict__ dinv,
                                               const unsigned short* __restrict__ slots,
                                               const unsigned char* __restrict__ h,
                                               const float* __restrict__ bias,
                                               unsigned char* __restrict__ outp) {
    int gid = blockIdx.x * blockDim.x + threadIdx.x;
    int n = gid >> 4;
    if (n >= N_NODES) return;
    int c = (gid & 15) << 3;

    float acc[8];
    gather_sum(cnt, slots, h, n, c, acc);

    float dn = dinv[n];
    u8x8 o;
    #pragma unroll
    for (int j = 0; j < 8; j++) {
        float z = fmaxf(acc[j] * dn + bias[c + j], 0.f);
        o[j] = f32_to_fp8(z * dn);
    }
    *reinterpret_cast<u8x8*>(outp + (size_t)n * DIM + c) = o;
}

// ================================================================ layer-2 gather (pre-scaled Z1') + mean-pool stage 1
// Agg(z1)[n] = dinv[n] * (Z1'[n] + sum Z1'[s]); W2/b2 deferred to pool2.
__global__ __launch_bounds__(256) void k_pull_pool(const int* __restrict__ cnt,
                                                   const float* __restrict__ dinv,
                                                   const unsigned short* __restrict__ slots,
                                                   const unsigned char* __restrict__ h,
                                                   const int* __restrict__ batch,
                                                   float* __restrict__ pooled) {
    __shared__ float pool_l[2][DIM];
    const int tid  = threadIdx.x;
    const int base = blockIdx.x * 64;
    const int c    = (tid & 15) << 3;

    pool_l[tid >> 7][tid & 127] = 0.f;
    __syncthreads();

    const int gmin = batch[min(base, N_NODES - 1)];

    #pragma unroll
    for (int r = 0; r < 4; r++) {
        int n = base + r * 16 + (tid >> 4);
        bool valid = n < N_NODES;
        int nn = min(n, N_NODES - 1);

        float acc[8];
        gather_sum(cnt, slots, h, nn, c, acc);
        float dn = dinv[nn];
        #pragma unroll
        for (int j = 0; j < 8; j++) acc[j] *= dn;          // = Agg(z1)[nn]
        if (!valid) {
            #pragma unroll
            for (int j = 0; j < 8; j++) acc[j] = 0.f;
        }

        const int g = batch[nn];
        const int d = g - gmin;

        if (__all(g == __shfl(g, 0))) {
            #pragma unroll
            for (int j = 0; j < 8; j++) {
                acc[j] += __shfl_xor(acc[j], 16);
                acc[j] += __shfl_xor(acc[j], 32);
            }
            if ((tid & 63) < 16) {
                if (d < 2) {
                    #pragma unroll
                    for (int j = 0; j < 8; j++) atomicAdd(&pool_l[d][c + j], acc[j]);
                } else {
                    #pragma unroll
                    for (int j = 0; j < 8; j++) atomicAdd(&pooled[g * DIM + c + j], acc[j]);
                }
            }
        } else {
            if (d < 2) {
                #pragma unroll
                for (int j = 0; j < 8; j++) atomicAdd(&pool_l[d][c + j], acc[j]);
            } else {
                #pragma unroll
                for (int j = 0; j < 8; j++) atomicAdd(&pooled[g * DIM + c + j], acc[j]);
            }
        }
    }
    __syncthreads();

    const int f = tid & 127;
    if (tid < 128) {
        atomicAdd(&pooled[gmin * DIM + f], pool_l[0][f]);
    } else {
        int last = min(base + 63, N_NODES - 1);
        if (batch[last] > gmin) atomicAdd(&pooled[(gmin + 1) * DIM + f], pool_l[1][f]);
    }
}

// ================================================================ pool stage 2: mean -> @W2+b2 -> @Wlin+blin -> relu (fp32)
__global__ __launch_bounds__(128) void k_pool2(const float* __restrict__ pooledA,
                                               const int* __restrict__ batch,
                                               const float* __restrict__ W2,
                                               const float* __restrict__ b2,
                                               const float* __restrict__ Wlin,
                                               const float* __restrict__ blin,
                                               float* __restrict__ out) {
    int g = blockIdx.x;
    int t = threadIdx.x;
    __shared__ int se[2];
    __shared__ float pa[DIM];
    __shared__ float z[DIM];
    if (t < 2) {
        int target = g + t;
        int lo = 0, hi = N_NODES;
        while (lo < hi) { int mid = (lo + hi) >> 1; if (batch[mid] < target) lo = mid + 1; else hi = mid; }
        se[t] = lo;
    }
    __syncthreads();
    float inv_cnt = 1.0f / fmaxf((float)(se[1] - se[0]), 1.0f);
    pa[t] = pooledA[g * DIM + t] * inv_cnt;
    __syncthreads();
    float acc = b2[t];
    #pragma unroll 8
    for (int k = 0; k < DIM; k++) acc += pa[k] * W2[k * DIM + t];
    z[t] = acc;
    __syncthreads();
    float acc2 = blin[t];
    #pragma unroll 8
    for (int k = 0; k < DIM; k++) acc2 += z[k] * Wlin[k * DIM + t];
    out[g * DIM + t] = fmaxf(acc2, 0.f);
}

// ================================================================ launch
extern "C" void kernel_launch(void* const* d_in, const int* in_sizes, int n_in,
                              void* d_out, int out_size, void* d_ws, size_t ws_size,
                              hipStream_t stream) {
    const float* x          = (const float*)d_in[0];
    const int*   edge_index = (const int*)d_in[1];
    const int*   batch      = (const int*)d_in[2];
    const float* W1         = (const float*)d_in[3];
    const float* b1         = (const float*)d_in[4];
    const float* W2         = (const float*)d_in[5];
    const float* b2         = (const float*)d_in[6];
    const float* Wlin       = (const float*)d_in[7];
    const float* blin       = (const float*)d_in[8];
    float*       out        = (float*)d_out;

    const int* src = edge_index;
    const int* dst = edge_index + N_EDGES;

    char* ws = (char*)d_ws;
    size_t off = 0;
    auto alloc = [&](size_t bytes) { void* p = ws + off; off = (off + bytes + 255) & ~255ULL; return p; };
    int*            cnt    = (int*)            alloc((size_t)N_NODES * 4);
    float*          dinv   = (float*)          alloc((size_t)N_NODES * 4);
    unsigned short* slots  = (unsigned short*) alloc((size_t)N_NODES * SLOTS * 2);
    float*          pooled = (float*)          alloc((size_t)NUM_GRAPHS * DIM * 4);
    unsigned short* Wt1    = (unsigned short*) alloc((size_t)DIM * DIM * 2);
    unsigned char*  H1     = (unsigned char*)  alloc((size_t)N_NODES * DIM);   // fp8 (pre-scaled after k_scale)
    unsigned char*  Z1     = (unsigned char*)  alloc((size_t)N_NODES * DIM);   // fp8 (pre-scaled)

    const int pullBlocks = (N_NODES * 16 + 255) / 256;      // 3125
    const int poolBlocks = (N_NODES + 63) / 64;             // 782

    // ---- weight prep (W1) + zero cnt/pooled ----
    k_prep_w<<<DIM, DIM, 0, stream>>>(W1, Wt1, cnt, pooled);

    // ---- GEMM1 (fp8 out) || adjacency fill (8 edges/thread) ----
    k_fill_gemm1<<<GEMM1_BLOCKS + FILL_BLOCKS, 512, 0, stream>>>(src, dst, cnt, slots, x, Wt1, H1);

    // ---- dinv + pre-scale H1 rows by dinv ----
    k_scale<<<pullBlocks, 256, 0, stream>>>(cnt, dinv, H1);

    // ---- layer 1 gather (pure row-sum) ----
    k_pull1<<<pullBlocks, 256, 0, stream>>>(cnt, dinv, slots, H1, b1, Z1);

    // ---- layer-2 gather (pure row-sum) + mean-pool stage 1 ----
    k_pull_pool<<<poolBlocks, 256, 0, stream>>>(cnt, dinv, slots, Z1, batch, pooled);

    // ---- pool stage 2: mean, @W2+b2, @Wlin+blin, relu ----
    k_pool2<<<NUM_GRAPHS, 128, 0, stream>>>(pooled, batch, W2, b2, Wlin, blin, out);
}